// Round 3
// baseline (133.906 us; speedup 1.0000x reference)
//
#include <hip/hip_runtime.h>
#include <math.h>

// Problem constants (from reference)
#define BB 8
#define NN 1024
#define CC 256
#define PARAM_DIM 16
#define EPS 1e-5f

// Dead-code collapse of the reference:
//   scores are broadcast over the softmax axis -> softmax is uniform ->
//   attention output == v (independent of q). So:
//     ctx = param_tokens @ Wparam + bparam          (B,256)
//     v   = layernorm(ctx) @ Wkv[:, C:2C]           (B,256)
//     y   = v @ Wout + bout                         (B,256)
//     out = img_tokens + y[:,None,:]                (B,N,C)

// Native vector type for nontemporal builtins.
typedef float f32x4 __attribute__((ext_vector_type(4)));

// 64-bit flag magic with two DISTINCT dword halves: a buffer-fill poison
// (single repeated dword pattern) can never match it, so the flag is
// self-initializing under per-iteration workspace poisoning. Stale-MAGIC +
// stale-y races are benign because y is bit-deterministic per iteration.
#define FLAG_MAGIC 0x13579BDFECA86420ull

// Single fused launch. 256 blocks x 1024 threads = exactly 1 block/CU
// worst case (16 waves, <=128 VGPR, 18.5 KB LDS) -> ALL blocks co-resident
// regardless of dispatch order -> spin-wait cannot deadlock.
//   blocks 0..7  : compute y[b] (R2 structure), publish device-scope flag,
//                  then do their slice of the broadcast-add.
//   blocks 8..255: issue img loads first (latency hides under the wait),
//                  poll their batch flag, add, store.
__global__ __launch_bounds__(1024) void fused_kernel(
    const float* __restrict__ param,    // (B, 16)
    const float* __restrict__ Wparam,   // (16, C)
    const float* __restrict__ bparam,   // (C,)
    const float* __restrict__ ctx_g,    // (C,)
    const float* __restrict__ ctx_b,    // (C,)
    const float* __restrict__ Wkv,      // (C, 2C)
    const float* __restrict__ Wout,     // (C, C)
    const float* __restrict__ bout,     // (C,)
    const f32x4* __restrict__ img4,     // (B*N*C/4)
    f32x4* __restrict__ out4,           // (B*N*C/4)
    float* yws,                         // ws: (B, C) y values
    unsigned long long* flags)          // ws+8192: B flag words
{
    const int bk = blockIdx.x;          // 0..255
    const int t  = threadIdx.x;         // 0..1023
    const int i0 = bk * 2048 + t * 2;   // this thread's float4 pair

    __shared__ float  sln[CC];          // layernormed ctx
    __shared__ float  sv[CC];           // v
    __shared__ float4 smp[1024];        // split-K partials (16 KB)
    __shared__ float  red[16];          // wave partial sums
    __shared__ float  p[PARAM_DIM];

    f32x4 a0, a1;
    if (bk >= BB) {
        // Add-only blocks: issue the streaming loads NOW; the HBM trip
        // overlaps the y-wait entirely.
        a0 = __builtin_nontemporal_load(&img4[i0]);
        a1 = __builtin_nontemporal_load(&img4[i0 + 1]);
    }

    if (bk < BB) {
        // ================= y-compute (one block per batch) =================
        const int b  = bk;
        const int c  = t & 255;         // output channel (4x replicated)
        const int c4 = t & 63;          // float4 column group
        const int k  = t >> 6;          // split-K index 0..15

        if (t < PARAM_DIM) p[t] = param[b * PARAM_DIM + t];

        // Wkv V-half register prefetch: overlaps the Wparam trip + both LN
        // reduction trees. 64 VGPRs, dead before the Wout prefetch lives.
        const float4* __restrict__ Wkv4 = (const float4*)Wkv;
        float4 wv[16];
        #pragma unroll
        for (int jj = 0; jj < 16; ++jj)
            wv[jj] = Wkv4[(k * 16 + jj) * 128 + 64 + c4];

        // ctx[c] = bparam[c] + sum_j p[j] * Wparam[j][c]
        float ctx = bparam[c];
        __syncthreads();                // p[] visible
        #pragma unroll
        for (int j = 0; j < PARAM_DIM; ++j)
            ctx = fmaf(p[j], Wparam[j * CC + c], ctx);

        // layernorm: block reduction over 1024 threads (each value 4x)
        float s = ctx;
        #pragma unroll
        for (int o = 32; o > 0; o >>= 1) s += __shfl_down(s, o, 64);
        if ((t & 63) == 0) red[t >> 6] = s;
        __syncthreads();
        float tot = 0.0f;
        #pragma unroll
        for (int i = 0; i < 16; ++i) tot += red[i];
        const float mean = tot * (1.0f / 1024.0f);

        const float d = ctx - mean;
        float s2 = d * d;
        __syncthreads();                // red[] reuse
        #pragma unroll
        for (int o = 32; o > 0; o >>= 1) s2 += __shfl_down(s2, o, 64);
        if ((t & 63) == 0) red[t >> 6] = s2;
        __syncthreads();
        tot = 0.0f;
        #pragma unroll
        for (int i = 0; i < 16; ++i) tot += red[i];
        const float var = tot * (1.0f / 1024.0f);

        const float ln = d * rsqrtf(var + EPS) * ctx_g[c] + ctx_b[c];
        if (t < CC) sln[c] = ln;
        __syncthreads();

        // v = ln @ Wkv[:, C:2C]  (split-K=16, prefetched weights)
        float4 acc = make_float4(0.f, 0.f, 0.f, 0.f);
        #pragma unroll
        for (int jj = 0; jj < 16; ++jj) {
            const float a = sln[k * 16 + jj];
            acc.x = fmaf(a, wv[jj].x, acc.x);
            acc.y = fmaf(a, wv[jj].y, acc.y);
            acc.z = fmaf(a, wv[jj].z, acc.z);
            acc.w = fmaf(a, wv[jj].w, acc.w);
        }
        smp[t] = acc;                   // index = k*64 + c4

        // Wout register prefetch: HBM trip overlaps the LDS reduce.
        const float4* __restrict__ Wout4 = (const float4*)Wout;
        float4 wo[16];
        #pragma unroll
        for (int jj = 0; jj < 16; ++jj)
            wo[jj] = Wout4[(k * 16 + jj) * 64 + c4];

        __syncthreads();
        if (t < 64) {                   // reduce 16 partials per column group
            float4 r = smp[c4];
            #pragma unroll
            for (int kk = 1; kk < 16; ++kk) {
                const float4 q = smp[kk * 64 + c4];
                r.x += q.x; r.y += q.y; r.z += q.z; r.w += q.w;
            }
            sv[c4 * 4 + 0] = r.x; sv[c4 * 4 + 1] = r.y;
            sv[c4 * 4 + 2] = r.z; sv[c4 * 4 + 3] = r.w;
        }
        __syncthreads();

        // y = v @ Wout + bout  (split-K=16, prefetched weights)
        acc = make_float4(0.f, 0.f, 0.f, 0.f);
        #pragma unroll
        for (int jj = 0; jj < 16; ++jj) {
            const float a = sv[k * 16 + jj];
            acc.x = fmaf(a, wo[jj].x, acc.x);
            acc.y = fmaf(a, wo[jj].y, acc.y);
            acc.z = fmaf(a, wo[jj].z, acc.z);
            acc.w = fmaf(a, wo[jj].w, acc.w);
        }
        smp[t] = acc;
        __syncthreads();
        if (t < 64) {
            float4 r = smp[c4];
            #pragma unroll
            for (int kk = 1; kk < 16; ++kk) {
                const float4 q = smp[kk * 64 + c4];
                r.x += q.x; r.y += q.y; r.z += q.z; r.w += q.w;
            }
            const float4 bo = ((const float4*)bout)[c4];
            r.x += bo.x; r.y += bo.y; r.z += bo.z; r.w += bo.w;
            ((float4*)yws)[b * 64 + c4] = r;
        }
        __syncthreads();                // all y stores issued

        // Publish: device-scope release so other XCDs' acquires see y.
        if (t == 0) {
            __threadfence();
            __hip_atomic_store(&flags[b], FLAG_MAGIC,
                               __ATOMIC_RELEASE, __HIP_MEMORY_SCOPE_AGENT);
        }

        // y-blocks issue their streaming loads now (late but only 3% of
        // the traffic; other 248 blocks have been saturating HBM meanwhile).
        a0 = __builtin_nontemporal_load(&img4[i0]);
        a1 = __builtin_nontemporal_load(&img4[i0 + 1]);
    }

    // ================= broadcast add (all 256 blocks) =================
    const int bb = bk >> 5;             // 32 blocks per batch
    if (t == 0) {
        // Agent-scope acquire: invalidates this CU's L1 + stale L2 lines,
        // so the block's subsequent normal y loads are fresh.
        while (__hip_atomic_load(&flags[bb], __ATOMIC_ACQUIRE,
                                 __HIP_MEMORY_SCOPE_AGENT) != FLAG_MAGIC)
            __builtin_amdgcn_s_sleep(2);
    }
    __syncthreads();

    const f32x4* y4 = (const f32x4*)yws;
    const int c0 = i0 & 63;             // even; pair stays in one row
    const f32x4 y0 = y4[bb * 64 + c0];
    const f32x4 y1 = y4[bb * 64 + c0 + 1];
    a0 += y0;
    a1 += y1;
    __builtin_nontemporal_store(a0, &out4[i0]);
    __builtin_nontemporal_store(a1, &out4[i0 + 1]);
}

extern "C" void kernel_launch(void* const* d_in, const int* in_sizes, int n_in,
                              void* d_out, int out_size, void* d_ws, size_t ws_size,
                              hipStream_t stream) {
    const float* img     = (const float*)d_in[0];   // (B, N, C)
    const float* param   = (const float*)d_in[1];   // (B, 16)
    // d_in[2] img_norm_g, d_in[3] img_norm_b, d_in[4] Wq -> dead code
    const float* Wparam  = (const float*)d_in[5];   // (16, C)
    const float* bparam  = (const float*)d_in[6];   // (C,)
    const float* ctx_g   = (const float*)d_in[7];   // (C,)
    const float* ctx_b   = (const float*)d_in[8];   // (C,)
    const float* Wkv     = (const float*)d_in[9];   // (C, 2C)
    const float* Wout    = (const float*)d_in[10];  // (C, C)
    const float* bout    = (const float*)d_in[11];  // (C,)
    float* out = (float*)d_out;

    float* yws = (float*)d_ws;                      // (B, C) = 8 KB
    unsigned long long* flags =
        (unsigned long long*)((char*)d_ws + 8192);  // B flag words

    fused_kernel<<<256, 1024, 0, stream>>>(param, Wparam, bparam, ctx_g, ctx_b,
                                           Wkv, Wout, bout,
                                           (const f32x4*)img, (f32x4*)out,
                                           yws, flags);
}

// Round 5
// 89.616 us; speedup vs baseline: 1.4942x; 1.4942x over previous
//
#include <hip/hip_runtime.h>
#include <math.h>

// Problem constants (from reference)
#define BB 8
#define NN 1024
#define CC 256
#define PARAM_DIM 16
#define EPS 1e-5f

// Dead-code collapse of the reference:
//   scores are broadcast over the softmax axis -> softmax is uniform ->
//   attention output == v (independent of q). So:
//     ctx = param_tokens @ Wparam + bparam          (B,256)
//     v   = layernorm(ctx) @ Wkv[:, C:2C]           (B,256)
//     y   = v @ Wout + bout                         (B,256)
//     out = img_tokens + y[:,None,:]                (B,N,C)

// Native vector type for nontemporal builtins (HIP float4 is a class type
// the builtin rejects; clang ext_vector_type is accepted).
typedef float f32x4 __attribute__((ext_vector_type(4)));

// One block per batch, 1024 threads, 16-way split-K matvecs.
// Prefetch Wkv into registers at kernel entry (overlaps the Wparam trip +
// both LN reduction trees) and issue Wout loads before the V-reduction
// barrier (overlaps the LDS reduce). Cuts the serial HBM round-trips on
// the critical path from 3 to ~1.3 (everything is cold every iteration
// because the harness's 256 MiB poison fills flush L2/L3).
// NOTE (R3 post-mortem): do NOT fuse these two kernels with a spin-wait —
// the producer/consumer flag poll serialized at the coherence point and
// regressed the fused dispatch to 56 us (280 GB/s). Two launches + ~1 us
// graph gap is strictly better.
__global__ __launch_bounds__(1024) void compute_y_kernel(
    const float* __restrict__ param,    // (B, 16)
    const float* __restrict__ Wparam,   // (16, C)
    const float* __restrict__ bparam,   // (C,)
    const float* __restrict__ ctx_g,    // (C,)
    const float* __restrict__ ctx_b,    // (C,)
    const float* __restrict__ Wkv,      // (C, 2C)
    const float* __restrict__ Wout,     // (C, C)
    const float* __restrict__ bout,     // (C,)
    float* __restrict__ y)              // (B, C) out
{
    const int b  = blockIdx.x;
    const int t  = threadIdx.x;         // 0..1023
    const int c  = t & 255;             // output channel (4x replicated)
    const int c4 = t & 63;              // float4 column group
    const int k  = t >> 6;              // split-K index 0..15

    __shared__ float  sln[CC];          // layernormed ctx
    __shared__ float  sv[CC];           // v
    __shared__ float4 smp[1024];        // split-K partials (16 KB)
    __shared__ float  red[16];          // wave partial sums
    __shared__ float  p[PARAM_DIM];

    if (t < PARAM_DIM) p[t] = param[b * PARAM_DIM + t];

    // ---- Wkv V-half register prefetch: independent of LN, issue NOW so the
    // HBM trip hides under ctx compute + two LN reduction trees. 64 VGPRs,
    // dead before the Wout prefetch goes live (stays under the 128 cap).
    const float4* __restrict__ Wkv4 = (const float4*)Wkv;
    float4 wv[16];
    #pragma unroll
    for (int jj = 0; jj < 16; ++jj)
        wv[jj] = Wkv4[(k * 16 + jj) * 128 + 64 + c4];

    // ---- ctx[c] = bparam[c] + sum_j p[j] * Wparam[j][c]  (replicated 4x) ----
    float ctx = bparam[c];
    __syncthreads();                    // p[] visible
    #pragma unroll
    for (int j = 0; j < PARAM_DIM; ++j)
        ctx = fmaf(p[j], Wparam[j * CC + c], ctx);

    // ---- layernorm: block reduction over 1024 threads (each value 4x) ----
    float s = ctx;
    #pragma unroll
    for (int o = 32; o > 0; o >>= 1) s += __shfl_down(s, o, 64);
    if ((t & 63) == 0) red[t >> 6] = s;
    __syncthreads();
    float tot = 0.0f;
    #pragma unroll
    for (int i = 0; i < 16; ++i) tot += red[i];
    const float mean = tot * (1.0f / 1024.0f);

    const float d = ctx - mean;
    float s2 = d * d;
    __syncthreads();                    // red[] reuse
    #pragma unroll
    for (int o = 32; o > 0; o >>= 1) s2 += __shfl_down(s2, o, 64);
    if ((t & 63) == 0) red[t >> 6] = s2;
    __syncthreads();
    tot = 0.0f;
    #pragma unroll
    for (int i = 0; i < 16; ++i) tot += red[i];
    const float var = tot * (1.0f / 1024.0f);

    const float ln = d * rsqrtf(var + EPS) * ctx_g[c] + ctx_b[c];
    if (t < CC) sln[c] = ln;
    __syncthreads();

    // ---- v = ln @ Wkv[:, C:2C]  (split-K=16, prefetched weights) ----
    float4 acc = make_float4(0.f, 0.f, 0.f, 0.f);
    #pragma unroll
    for (int jj = 0; jj < 16; ++jj) {
        const float a = sln[k * 16 + jj];
        acc.x = fmaf(a, wv[jj].x, acc.x);
        acc.y = fmaf(a, wv[jj].y, acc.y);
        acc.z = fmaf(a, wv[jj].z, acc.z);
        acc.w = fmaf(a, wv[jj].w, acc.w);
    }
    smp[t] = acc;                       // index = k*64 + c4

    // ---- Wout register prefetch: issue before the reduction barrier so the
    // HBM trip overlaps the LDS reduce of the V partials. Reuses wv's regs.
    const float4* __restrict__ Wout4 = (const float4*)Wout;  // row j = 64 float4
    float4 wo[16];
    #pragma unroll
    for (int jj = 0; jj < 16; ++jj)
        wo[jj] = Wout4[(k * 16 + jj) * 64 + c4];

    __syncthreads();
    if (t < 64) {                       // reduce 16 partials per column group
        float4 r = smp[c4];
        #pragma unroll
        for (int kk = 1; kk < 16; ++kk) {
            const float4 q = smp[kk * 64 + c4];
            r.x += q.x; r.y += q.y; r.z += q.z; r.w += q.w;
        }
        sv[c4 * 4 + 0] = r.x; sv[c4 * 4 + 1] = r.y;
        sv[c4 * 4 + 2] = r.z; sv[c4 * 4 + 3] = r.w;
    }
    __syncthreads();

    // ---- y = v @ Wout + bout  (split-K=16, prefetched weights) ----
    acc = make_float4(0.f, 0.f, 0.f, 0.f);
    #pragma unroll
    for (int jj = 0; jj < 16; ++jj) {
        const float a = sv[k * 16 + jj];
        acc.x = fmaf(a, wo[jj].x, acc.x);
        acc.y = fmaf(a, wo[jj].y, acc.y);
        acc.z = fmaf(a, wo[jj].z, acc.z);
        acc.w = fmaf(a, wo[jj].w, acc.w);
    }
    smp[t] = acc;
    __syncthreads();
    if (t < 64) {
        float4 r = smp[c4];
        #pragma unroll
        for (int kk = 1; kk < 16; ++kk) {
            const float4 q = smp[kk * 64 + c4];
            r.x += q.x; r.y += q.y; r.z += q.z; r.w += q.w;
        }
        const float4 bo = ((const float4*)bout)[c4];
        r.x += bo.x; r.y += bo.y; r.z += bo.z; r.w += bo.w;
        ((float4*)y)[b * 64 + c4] = r;
    }
}

// out[b,n,:] = img[b,n,:] + y[b,:] — 2 float4/thread (32 B/lane),
// nontemporal on the streamed 16.8 MB (img read once, out never re-read),
// y (8 KB) through the cache as a normal load.
__global__ __launch_bounds__(256) void bcast_add_kernel(
    const f32x4* __restrict__ img4,
    const f32x4* __restrict__ y4,       // (B, 64) f32x4 rows
    f32x4* __restrict__ out4)
{
    const int gid = blockIdx.x * blockDim.x + threadIdx.x;  // < 262144
    const int i0  = gid * 2;            // pair never crosses a batch boundary
    const int b   = i0 >> 16;           // N*C/4 = 65536 float4 per batch
    const int c0  = i0 & 63;            // even; c1 = c0+1 in same row

    f32x4 a0 = __builtin_nontemporal_load(&img4[i0]);
    f32x4 a1 = __builtin_nontemporal_load(&img4[i0 + 1]);
    const f32x4 y0 = y4[b * 64 + c0];
    const f32x4 y1 = y4[b * 64 + c0 + 1];
    a0 += y0;
    a1 += y1;
    __builtin_nontemporal_store(a0, &out4[i0]);
    __builtin_nontemporal_store(a1, &out4[i0 + 1]);
}

extern "C" void kernel_launch(void* const* d_in, const int* in_sizes, int n_in,
                              void* d_out, int out_size, void* d_ws, size_t ws_size,
                              hipStream_t stream) {
    const float* img     = (const float*)d_in[0];   // (B, N, C)
    const float* param   = (const float*)d_in[1];   // (B, 16)
    // d_in[2] img_norm_g, d_in[3] img_norm_b, d_in[4] Wq -> dead code
    const float* Wparam  = (const float*)d_in[5];   // (16, C)
    const float* bparam  = (const float*)d_in[6];   // (C,)
    const float* ctx_g   = (const float*)d_in[7];   // (C,)
    const float* ctx_b   = (const float*)d_in[8];   // (C,)
    const float* Wkv     = (const float*)d_in[9];   // (C, 2C)
    const float* Wout    = (const float*)d_in[10];  // (C, C)
    const float* bout    = (const float*)d_in[11];  // (C,)
    float* out = (float*)d_out;
    float* y   = (float*)d_ws;                      // (B, C) scratch = 8 KB

    compute_y_kernel<<<BB, 1024, 0, stream>>>(param, Wparam, bparam, ctx_g, ctx_b,
                                              Wkv, Wout, bout, y);

    const int total_pairs = BB * NN * CC / 8;       // 262144 threads, 2 float4 each
    bcast_add_kernel<<<total_pairs / 256, 256, 0, stream>>>(
        (const f32x4*)img, (const f32x4*)y, (f32x4*)out);
}